// Round 23
// baseline (128.585 us; speedup 1.0000x reference)
//
#include <hip/hip_runtime.h>

// ---------------------------------------------------------------------------
// SE3 conv layer, 6-dispatch pipeline (R23: LINEAR edge writes experiment):
//   memset -> prep (bfrag + w1frag f16 pack + dst histogram) -> scan (int4)
//   -> scatter (eord only: CSR edge-id list) 
//   -> edge (1-wave blocks, NO atomics, rows written LINEARLY at index e)
//   -> gather (indirect rows[eord[i]] reads; rows fit in L3)
// FUSED row (128 B, EDGE-ordered), one per edge:
//   words 0-15 : (l0[w], l1[w]) f16 pairs
//   words 16-23: (l2[2t], l2[2t+1]) f16 pairs
//   words 24-28: packed sh: (s0,s1)(s2,s3)(s4,s5)(s6,s7)(s8,0);  29-31 pad.
// ws: [ rows E*32 u32 | offs pad32768 | curs N | eord E | bfrag+pad | w1frag ]
// R10: VGPR budget discipline. R11: LDS broadcast. R14: zero-padded scan.
// R17: clamped gather groups amplify loads. R21: big waves starve SIMDs.
// R23 experiment: isolate scattered-WRITE cost (edge linear writes + gather
// random L3-resident reads). If edge stays ~64us, writes are exonerated.
// ---------------------------------------------------------------------------

typedef _Float16 f16x2 __attribute__((ext_vector_type(2)));
typedef _Float16 f16x8 __attribute__((ext_vector_type(8)));
typedef __fp16  g16x2 __attribute__((ext_vector_type(2)));   // cvt_pkrtz result type
typedef float f32x4 __attribute__((ext_vector_type(4)));

union AFrag { unsigned int u[4]; f16x2 h2[4]; f16x8 v; };
union BFrag { uint4 u4; f16x8 v; };
union HW { g16x2 g; f16x2 f; unsigned int u; };

// ----------- prep: bfrag pack + W1 frag pack + dst histogram ----------------

__global__ __launch_bounds__(256)
void prep_kernel(const float* __restrict__ W2, const float* __restrict__ W1,
                 _Float16* __restrict__ bfrag, _Float16* __restrict__ w1frag,
                 const int* __restrict__ ei, int* __restrict__ counts, int E) {
    int t = blockIdx.x * 256 + threadIdx.x;
    if (t < E) atomicAdd(&counts[ei[E + t] + 1], 1);
    if (t < 96 * 512) {
        int f = t >> 9;
        int rr = t & 511;
        int lane = rr >> 3, j = rr & 7;
        int ks = f / 3, nt = f - 3 * ks;
        int q = lane >> 4, c = lane & 15;
        int ku = ks * 32 + q * 8 + j;
        int k = ku >> 4, u = ku & 15;
        int n = nt * 16 + c;
        int l = n >> 4, v = n & 15;
        float val = W2[(size_t)k * 768 + l * 256 + u * 16 + v] * 0.03125f;
        bfrag[t] = (_Float16)val;
    }
    if (t < 2048) {
        int nt = t >> 9, rr = t & 511;
        int lane = rr >> 3, j = rr & 7;
        int q = lane >> 4, c = lane & 15;
        int u = q * 8 + j;
        float val = (q < 2) ? W1[u * 64 + nt * 16 + c] * 0.25f : 0.0f;
        w1frag[t] = (_Float16)val;
    }
}

// int4-vectorized inclusive scan over a ZERO-PADDED region (n_pad % 32768 == 0).
__global__ __launch_bounds__(1024)
void scan_kernel(int* __restrict__ data, int n_pad) {
    __shared__ int wsum[16];
    __shared__ int carry_s;
    int tid = threadIdx.x, lane = tid & 63, wid = tid >> 6;
    if (tid == 0) carry_s = 0;
    __syncthreads();
    for (int base = 0; base < n_pad; base += 32768) {
        int beg = base + tid * 32;
        int4 c0[8];
        #pragma unroll
        for (int j = 0; j < 8; ++j)
            c0[j] = *(const int4*)(data + beg + j * 4);
        int s = 0;
        #pragma unroll
        for (int j = 0; j < 8; ++j) s += c0[j].x + c0[j].y + c0[j].z + c0[j].w;

        int v = s;
        #pragma unroll
        for (int off = 1; off < 64; off <<= 1) {
            int t = __shfl_up(v, off, 64);
            if (lane >= off) v += t;
        }
        if (lane == 63) wsum[wid] = v;
        __syncthreads();
        if (wid == 0 && lane < 16) {
            int w = wsum[lane];
            #pragma unroll
            for (int off = 1; off < 16; off <<= 1) {
                int t = __shfl_up(w, off, 16);
                if (lane >= off) w += t;
            }
            wsum[lane] = w;
        }
        __syncthreads();
        int run = carry_s + (v - s) + (wid > 0 ? wsum[wid - 1] : 0);
        #pragma unroll
        for (int j = 0; j < 8; ++j) {
            int4 o;
            run += c0[j].x; o.x = run;
            run += c0[j].y; o.y = run;
            run += c0[j].z; o.z = run;
            run += c0[j].w; o.w = run;
            *(int4*)(data + beg + j * 4) = o;
        }
        __syncthreads();
        if (tid == 1023) carry_s = run;
        __syncthreads();
    }
}

// scatter: build CSR edge-id list only (4 B per edge).
__global__ __launch_bounds__(256)
void scatter_kernel(const int* __restrict__ ei, const int* __restrict__ offs,
                    int* __restrict__ cursor, int* __restrict__ eord, int E) {
    int e = blockIdx.x * blockDim.x + threadIdx.x;
    if (e >= E) return;
    int dst = ei[E + e];
    int p = offs[dst] + atomicAdd(&cursor[dst], 1);
    eord[p] = e;
}

// --------------------------- MFMA edge kernel ------------------------------
// 1 wave per block; wave owns 64 edges (4 M-tiles of 16). Barrier-free.
// NO atomics; rows written LINEARLY at index e.

__global__ __launch_bounds__(64, 4)
void edge_mfma_kernel(const float* __restrict__ nf, const int* __restrict__ ei,
                      const float* __restrict__ radial,
                      const _Float16* __restrict__ w1frag,
                      const float* __restrict__ sh,
                      const _Float16* __restrict__ bfrag,
                      unsigned int* __restrict__ rows, int E) {
    __shared__ unsigned int h_lds[64][32];   // f16 pairs (k=2t,2t+1), XOR-swizzled

    int lane = threadIdx.x & 63;
    int r_ = lane & 15;
    int q  = lane >> 4;
    int qh = q >> 1;
    int ul = (q & 1) * 8;
    unsigned int sel = qh ? 0x03020302u : 0x01000100u;

    int ebase = blockIdx.x * 64;

    // ---- phase 0: x rows for the wave's 4 M-tiles, f16 pack ----
    HW xp[4][4];
    #pragma unroll
    for (int m = 0; m < 4; ++m) {
        int e = ebase + m * 16 + r_; if (e >= E) e = E - 1;
        int src = ei[e];
        const float* xpp = nf + (size_t)src * 16 + ul;
        float4 a = *(const float4*)xpp;
        float4 b = *(const float4*)(xpp + 4);
        xp[m][0].g = __builtin_amdgcn_cvt_pkrtz(a.x, a.y);
        xp[m][1].g = __builtin_amdgcn_cvt_pkrtz(a.z, a.w);
        xp[m][2].g = __builtin_amdgcn_cvt_pkrtz(b.x, b.y);
        xp[m][3].g = __builtin_amdgcn_cvt_pkrtz(b.z, b.w);
    }

    // ---- phase 0.5: lane = edge; pack sh into OWN row (linear write) ----
    {
        int e = ebase + lane;
        if (e < E) {
            const float* s = sh + (size_t)e * 9;
            float4 s03 = *(const float4*)s;
            float4 s47 = *(const float4*)(s + 4);
            float s8 = s[8];
            unsigned int* d = rows + (size_t)e * 32 + 24;
            HW w0, w1, w2, w3, w4;
            w0.g = __builtin_amdgcn_cvt_pkrtz(s03.x, s03.y);
            w1.g = __builtin_amdgcn_cvt_pkrtz(s03.z, s03.w);
            w2.g = __builtin_amdgcn_cvt_pkrtz(s47.x, s47.y);
            w3.g = __builtin_amdgcn_cvt_pkrtz(s47.z, s47.w);
            w4.g = __builtin_amdgcn_cvt_pkrtz(s8, 0.0f);
            d[0] = w0.u; d[1] = w1.u; d[2] = w2.u; d[3] = w3.u; d[4] = w4.u;
        }
    }

    // ---- phase 1: radial MLP via MFMA: z[64e][64k] = radial @ W1frag ----
    {
        BFrag wf[4];
        #pragma unroll
        for (int nt = 0; nt < 4; ++nt)
            wf[nt].u4 = *(const uint4*)(w1frag + (size_t)nt * 512 + lane * 8);

        #pragma unroll
        for (int m = 0; m < 4; ++m) {
            AFrag ra;
            if (q < 2) {
                int e = ebase + m * 16 + r_; if (e >= E) e = E - 1;
                const float* rp = radial + (size_t)e * 16 + q * 8;
                float4 a = *(const float4*)rp;
                float4 b = *(const float4*)(rp + 4);
                HW t0, t1, t2, t3;
                t0.g = __builtin_amdgcn_cvt_pkrtz(a.x, a.y);
                t1.g = __builtin_amdgcn_cvt_pkrtz(a.z, a.w);
                t2.g = __builtin_amdgcn_cvt_pkrtz(b.x, b.y);
                t3.g = __builtin_amdgcn_cvt_pkrtz(b.z, b.w);
                ra.u[0] = t0.u; ra.u[1] = t1.u; ra.u[2] = t2.u; ra.u[3] = t3.u;
            } else {
                ra.u[0] = 0; ra.u[1] = 0; ra.u[2] = 0; ra.u[3] = 0;
            }
            #pragma unroll
            for (int nt = 0; nt < 4; ++nt) {
                f32x4 z4 = __builtin_amdgcn_mfma_f32_16x16x32_f16(
                    ra.v, wf[nt].v, (f32x4){0.f, 0.f, 0.f, 0.f}, 0, 0, 0);
                #pragma unroll
                for (int i = 0; i < 4; ++i) {
                    float z = z4[i];
                    float h = z * __builtin_amdgcn_rcpf(1.0f + __expf(-z));  // silu
                    float hn = __shfl_xor(h, 1);
                    if (!(r_ & 1)) {
                        int el = m * 16 + q * 4 + i;
                        HW w; w.g = __builtin_amdgcn_cvt_pkrtz(h, hn);  // (k, k+1)
                        h_lds[el][((nt << 3) + (r_ >> 1)) ^ (el & 31)] = w.u;
                    }
                }
            }
        }
    }

    // ---- phase 2: K-loop, 32 steps of K=32; B-frags double-buffered ----
    f32x4 acc[4][3];
    #pragma unroll
    for (int m = 0; m < 4; ++m)
        #pragma unroll
        for (int nt = 0; nt < 3; ++nt)
            acc[m][nt] = (f32x4){0.f, 0.f, 0.f, 0.f};

    auto compute = [&](int ks, BFrag (&b)[3]) {
        #pragma unroll
        for (int m = 0; m < 4; ++m) {
            int el = m * 16 + r_;
            unsigned int hw = h_lds[el][ks ^ (el & 31)];
            HW hv; hv.u = __builtin_amdgcn_perm(hw, hw, sel);
            AFrag a;
            #pragma unroll
            for (int p2 = 0; p2 < 4; ++p2)
                a.h2[p2] = hv.f * xp[m][p2].f;
            #pragma unroll
            for (int nt = 0; nt < 3; ++nt)
                acc[m][nt] = __builtin_amdgcn_mfma_f32_16x16x32_f16(a.v, b[nt].v, acc[m][nt], 0, 0, 0);
        }
    };

    BFrag bA[3], bB[3];
    #pragma unroll
    for (int nt = 0; nt < 3; ++nt)
        bA[nt].u4 = *(const uint4*)(bfrag + (size_t)nt * 512 + lane * 8);
    for (int ks = 0; ks < 32; ks += 2) {
        #pragma unroll
        for (int nt = 0; nt < 3; ++nt)
            bB[nt].u4 = *(const uint4*)(bfrag + (size_t)((ks + 1) * 3 + nt) * 512 + lane * 8);
        compute(ks, bA);
        #pragma unroll
        for (int nt = 0; nt < 3; ++nt)
            bA[nt].u4 = *(const uint4*)(bfrag + (size_t)((ks + 2) * 3 + nt) * 512 + lane * 8);
        compute(ks + 1, bB);
    }

    // ---- epilogue: C layout col=r_, row=q*4+i; LINEAR 128-B rows at e ----
    _Float16* rowh = (_Float16*)rows;
    #pragma unroll
    for (int m = 0; m < 4; ++m) {
        #pragma unroll
        for (int i = 0; i < 4; ++i) {
            int el = m * 16 + q * 4 + i;
            int e = ebase + el;
            if (e < E) {
                HW pr; pr.g = __builtin_amdgcn_cvt_pkrtz(acc[m][0][i], acc[m][1][i]);
                rows[(size_t)e * 32 + r_] = pr.u;
                rowh[(size_t)e * 64 + 32 + r_] = (_Float16)acc[m][2][i];
            }
        }
    }
}

// ------------------------------ gather -------------------------------------
// Rows are EDGE-ordered; CSR via eord indirection. rows (38 MB) is L3-resident
// so the random row reads are L3 hits. Lane w<16 owns word w; lane 16+t owns
// word 16+t; lanes 24-47 process the pair's second edge.

__global__ __launch_bounds__(256)
void gather_kernel(const unsigned int* __restrict__ rows,
                   const int* __restrict__ eord,
                   const int* __restrict__ offs,
                   const float* __restrict__ nf, const float* __restrict__ Wsi,
                   float* __restrict__ out, int N) {
    int node = blockIdx.x * 4 + (threadIdx.x >> 6);
    if (node >= N) return;
    int lane = threadIdx.x & 63;
    int half = (lane >= 24 && lane < 48) ? 1 : 0;
    int w = lane - half * 24;              // word index for lanes < 48
    bool active = lane < 48;
    bool isP = active && (w < 16);
    bool isQ = active && (w >= 16) && (w < 24);
    int t = w - 16;

    HW accP0, accP1; accP0.u = 0; accP1.u = 0;
    HW accQ0, accQ1, accQ2, accQ3, accQ4, accQ5;
    accQ0.u = accQ1.u = accQ2.u = accQ3.u = accQ4.u = accQ5.u = 0;

    int off = offs[node], end = offs[node + 1];
    int i = off;

    auto do_pair = [&](int ibase, bool pred) {
        int idx = ibase + half;
        bool valid = !pred || (idx < end);
        int ic = valid ? idx : ibase;      // clamp to first of pair
        int er = eord[ic];                 // broadcast within half-group
        const unsigned int* rb = rows + (size_t)er * 32;
        unsigned int M = 0, Sa = 0, Sb = 0, Sc = 0;
        if (active) M = rb[w];
        if (isP) { Sa = rb[24]; Sb = rb[25]; }
        if (isQ) { Sa = rb[26]; Sb = rb[27]; Sc = rb[28]; }
        if (!valid) { Sa = 0; Sb = 0; Sc = 0; }
        HW m_, sa, sb, sc; m_.u = M; sa.u = Sa; sb.u = Sb; sc.u = Sc;
        if (isP) {
            accP0.f += m_.f * sa.f;                                    // (l0*s0, l1*s1)
            HW mh; mh.u = __builtin_amdgcn_perm(M, M, 0x03020302u);    // (l1,l1)
            accP1.f += mh.f * sb.f;                                    // (l1*s2, l1*s3)
        }
        if (isQ) {
            HW ma; ma.u = __builtin_amdgcn_perm(M, M, 0x01000100u);    // (va,va)
            HW mb; mb.u = __builtin_amdgcn_perm(M, M, 0x03020302u);    // (vb,vb)
            accQ0.f += ma.f * sa.f;   // va*(s4,s5)
            accQ1.f += ma.f * sb.f;   // va*(s6,s7)
            accQ2.f += ma.f * sc.f;   // va*(s8,0)
            accQ3.f += mb.f * sa.f;
            accQ4.f += mb.f * sb.f;
            accQ5.f += mb.f * sc.f;
        }
    };

    // main: 4 pairs (8 edges) per round, no predication (loads hoist freely)
    for (; i + 7 < end; i += 8) {
        #pragma unroll
        for (int jp = 0; jp < 4; ++jp) do_pair(i + 2 * jp, false);
    }
    // tail: predicated pairs
    for (; i < end; i += 2) do_pair(i, true);

    // fold half=1 into half=0 lanes (lanes >=48 hold zeros)
    {
        int o;
        o = __shfl((int)accP0.u, lane + 24, 64); if (lane < 24) { HW h_; h_.u = (unsigned)o; accP0.f += h_.f; }
        o = __shfl((int)accP1.u, lane + 24, 64); if (lane < 24) { HW h_; h_.u = (unsigned)o; accP1.f += h_.f; }
        o = __shfl((int)accQ0.u, lane + 24, 64); if (lane < 24) { HW h_; h_.u = (unsigned)o; accQ0.f += h_.f; }
        o = __shfl((int)accQ1.u, lane + 24, 64); if (lane < 24) { HW h_; h_.u = (unsigned)o; accQ1.f += h_.f; }
        o = __shfl((int)accQ2.u, lane + 24, 64); if (lane < 24) { HW h_; h_.u = (unsigned)o; accQ2.f += h_.f; }
        o = __shfl((int)accQ3.u, lane + 24, 64); if (lane < 24) { HW h_; h_.u = (unsigned)o; accQ3.f += h_.f; }
        o = __shfl((int)accQ4.u, lane + 24, 64); if (lane < 24) { HW h_; h_.u = (unsigned)o; accQ4.f += h_.f; }
        o = __shfl((int)accQ5.u, lane + 24, 64); if (lane < 24) { HW h_; h_.u = (unsigned)o; accQ5.f += h_.f; }
    }

    if (lane >= 24) return;
    float* orow = out + (size_t)node * 144;
    if (w < 16) {
        float c0 = (float)accP0.f[0];          // ch w (l0)
        float c1 = (float)accP0.f[1];          // ch 16+3w
        float c2 = (float)accP1.f[0];          // ch 16+3w+1
        float c3 = (float)accP1.f[1];          // ch 16+3w+2
        const float* xr = nf + (size_t)node * 16;
        float si = 0.0f;
        #pragma unroll
        for (int u = 0; u < 16; ++u)
            si = fmaf(xr[u], Wsi[u * 16 + w], si);
        c0 = fmaf(si, 0.25f, c0);
        orow[w] = c0;
        orow[16 + 3 * w + 0] = c1;
        orow[16 + 3 * w + 1] = c2;
        orow[16 + 3 * w + 2] = c3;
    } else {
        float* qp = orow + 64 + 10 * t;
        qp[0] = (float)accQ0.f[0]; qp[1] = (float)accQ0.f[1];
        qp[2] = (float)accQ1.f[0]; qp[3] = (float)accQ1.f[1];
        qp[4] = (float)accQ2.f[0];
        qp[5] = (float)accQ3.f[0]; qp[6] = (float)accQ3.f[1];
        qp[7] = (float)accQ4.f[0]; qp[8] = (float)accQ4.f[1];
        qp[9] = (float)accQ5.f[0];
    }
}

// ------------------------- fallback (atomic path) --------------------------

__global__ __launch_bounds__(256)
void si_init_kernel(const float* __restrict__ nf, const float* __restrict__ Wsi,
                    float* __restrict__ out, int N) {
    int t = blockIdx.x * blockDim.x + threadIdx.x;
    int total = N * 144;
    if (t >= total) return;
    int n = t / 144;
    int c = t - n * 144;
    float val = 0.0f;
    if (c < 16) {
        const float* xr = nf + n * 16;
        #pragma unroll
        for (int u = 0; u < 16; ++u)
            val = fmaf(xr[u], Wsi[u * 16 + c], val);
        val *= 0.25f;
    }
    out[t] = val;
}

__global__ __launch_bounds__(256)
void edge_kernel_atomic(const float* __restrict__ nf, const int* __restrict__ ei,
                        const float* __restrict__ sh, const float* __restrict__ radial,
                        const float* __restrict__ W1, const float* __restrict__ W2,
                        float* __restrict__ out, int E) {
    int e = blockIdx.x * blockDim.x + threadIdx.x;
    if (e >= E) return;
    int src = ei[e];
    int dst = ei[E + e];
    float r[16], x[16];
    #pragma unroll
    for (int u = 0; u < 16; ++u) r[u] = radial[e * 16 + u] * 0.25f;
    #pragma unroll
    for (int u = 0; u < 16; ++u) x[u] = nf[src * 16 + u] * 0.03125f;
    float acc[48];
    #pragma unroll
    for (int j = 0; j < 48; ++j) acc[j] = 0.0f;
    for (int k = 0; k < 64; ++k) {
        float z = 0.0f;
        #pragma unroll
        for (int u = 0; u < 16; ++u) z = fmaf(r[u], W1[u * 64 + k], z);
        float hk = z / (1.0f + __expf(-z));
        const float* w2k = W2 + k * 768;
        #pragma unroll 4
        for (int u = 0; u < 16; ++u) {
            float p = hk * x[u];
            const float* w = w2k + u * 16;
            #pragma unroll
            for (int l = 0; l < 3; ++l)
                #pragma unroll
                for (int v = 0; v < 16; ++v)
                    acc[l * 16 + v] = fmaf(p, w[l * 256 + v], acc[l * 16 + v]);
        }
    }
    const float* she = sh + e * 9;
    float* orow = out + (long)dst * 144;
    #pragma unroll
    for (int v = 0; v < 16; ++v) atomicAdd(&orow[v], acc[v] * she[0]);
    #pragma unroll
    for (int v = 0; v < 16; ++v)
        for (int m = 0; m < 3; ++m)
            atomicAdd(&orow[16 + v * 3 + m], acc[16 + v] * she[1 + m]);
    #pragma unroll
    for (int v = 0; v < 16; ++v)
        for (int m = 0; m < 5; ++m)
            atomicAdd(&orow[64 + v * 5 + m], acc[32 + v] * she[4 + m]);
}

// ---------------------------------------------------------------------------

extern "C" void kernel_launch(void* const* d_in, const int* in_sizes, int n_in,
                              void* d_out, int out_size, void* d_ws, size_t ws_size,
                              hipStream_t stream) {
    const float* nf     = (const float*)d_in[0];
    const int*   ei     = (const int*)  d_in[1];
    const float* sh     = (const float*)d_in[2];
    const float* radial = (const float*)d_in[3];
    const float* W1     = (const float*)d_in[4];
    const float* W2     = (const float*)d_in[5];
    const float* Wsi    = (const float*)d_in[6];
    float* out = (float*)d_out;

    const int N = in_sizes[0] / 16;
    const int E = in_sizes[1] / 2;

    int n_scan = N + 1;
    int n_pad  = (n_scan + 32767) & ~32767;

    size_t rows_bytes = (size_t)E * 128;                     // fused 128-B rows
    size_t offs_bytes = (size_t)n_pad * sizeof(int);
    size_t curs_bytes = (size_t)N * sizeof(int);
    size_t eord_bytes = (size_t)E * sizeof(int);
    size_t bfrag_off  = (rows_bytes + offs_bytes + curs_bytes + eord_bytes + 127) & ~(size_t)127;
    size_t bfrag_bytes = 102 * 512 * sizeof(_Float16);       // 96KB + pad (prefetch)
    size_t w1f_off    = bfrag_off + bfrag_bytes;
    size_t w1f_bytes  = 2048 * sizeof(_Float16);             // 4 KB
    size_t need = w1f_off + w1f_bytes;

    if (ws_size < need) {
        int total = N * 144;
        hipLaunchKernelGGL(si_init_kernel, dim3((total + 255) / 256), dim3(256), 0, stream,
                           nf, Wsi, out, N);
        hipLaunchKernelGGL(edge_kernel_atomic, dim3((E + 255) / 256), dim3(256), 0, stream,
                           nf, ei, sh, radial, W1, W2, out, E);
        return;
    }

    char* wsb = (char*)d_ws;
    unsigned int* rows = (unsigned int*)wsb;
    int*   offs = (int*)(wsb + rows_bytes);
    int*   curs = (int*)(wsb + rows_bytes + offs_bytes);
    int*   eord = (int*)(wsb + rows_bytes + offs_bytes + curs_bytes);
    _Float16* bfrag = (_Float16*)(wsb + bfrag_off);
    _Float16* w1frag = (_Float16*)(wsb + w1f_off);

    (void)hipMemsetAsync(offs, 0, offs_bytes + curs_bytes, stream);

    int eb256 = (E + 255) / 256;
    hipLaunchKernelGGL(prep_kernel, dim3(eb256), dim3(256), 0, stream,
                       W2, W1, bfrag, w1frag, ei, offs, E);
    hipLaunchKernelGGL(scan_kernel, dim3(1), dim3(1024), 0, stream, offs, n_pad);
    hipLaunchKernelGGL(scatter_kernel, dim3(eb256), dim3(256), 0, stream,
                       ei, offs, curs, eord, E);
    int eb64 = (E + 63) / 64;
    hipLaunchKernelGGL(edge_mfma_kernel, dim3(eb64), dim3(64), 0, stream,
                       nf, ei, radial, w1frag, sh, bfrag, rows, E);
    hipLaunchKernelGGL(gather_kernel, dim3((N + 3) / 4), dim3(256), 0, stream,
                       rows, eord, offs, nf, Wsi, out, N);
}

// Round 24
// 109.457 us; speedup vs baseline: 1.1748x; 1.1748x over previous
//
#include <hip/hip_runtime.h>

// ---------------------------------------------------------------------------
// SE3 conv layer, 5-dispatch pipeline (FINAL = R22 config, best: 109.5 us):
//   memset -> prep (bfrag + w1frag f16 pack + dst histogram) -> scan (int4)
//   -> edge (1-wave blocks, 64 edges/wave: CSR claim + MFMA radial-MLP +
//            MFMA contraction w/ register double-buffered B-frags)
//   -> gather (u32 packed-f16 segmented reduction + self-interaction)
// FUSED row (128 B, CSR-ordered), one per edge:
//   words 0-15 : (l0[w], l1[w]) f16 pairs
//   words 16-23: (l2[2t], l2[2t+1]) f16 pairs
//   words 24-28: packed sh: (s0,s1)(s2,s3)(s4,s5)(s6,s7)(s8,0);  29-31 pad.
// ws: [ rows E*32 u32 | offs pad32768 | curs N | bfrag 96KB+pad | w1frag ]
// Session lessons baked in:
//  R10: VGPR cap + wide state -> scratch spills (FETCH 19->124MB).
//  R11: "uniform" global loads don't scalarize; LDS broadcast is reliable.
//  R9:  CSR-claim must be lane-parallel, not per-fragment epilogue-serial.
//  R14: scan needs zero-padded unconditional int4 (tail guard dropped counts).
//  R17: clamped gather groups amplify loads 1.6x -> 2x regress.
//  R21: 128-edge waves starve SIMDs (Occ 15%).
//  R23: scattered edge writes cost only ~5us; read-side permutation costs
//       ~20us -> write-side permutation (this config) is the right topology.
// ---------------------------------------------------------------------------

typedef _Float16 f16x2 __attribute__((ext_vector_type(2)));
typedef _Float16 f16x8 __attribute__((ext_vector_type(8)));
typedef __fp16  g16x2 __attribute__((ext_vector_type(2)));   // cvt_pkrtz result type
typedef float f32x4 __attribute__((ext_vector_type(4)));

union AFrag { unsigned int u[4]; f16x2 h2[4]; f16x8 v; };
union BFrag { uint4 u4; f16x8 v; };
union HW { g16x2 g; f16x2 f; unsigned int u; };

// ----------- prep: bfrag pack + W1 frag pack + dst histogram ----------------

__global__ __launch_bounds__(256)
void prep_kernel(const float* __restrict__ W2, const float* __restrict__ W1,
                 _Float16* __restrict__ bfrag, _Float16* __restrict__ w1frag,
                 const int* __restrict__ ei, int* __restrict__ counts, int E) {
    int t = blockIdx.x * 256 + threadIdx.x;
    if (t < E) atomicAdd(&counts[ei[E + t] + 1], 1);
    if (t < 96 * 512) {
        int f = t >> 9;
        int rr = t & 511;
        int lane = rr >> 3, j = rr & 7;
        int ks = f / 3, nt = f - 3 * ks;
        int q = lane >> 4, c = lane & 15;
        int ku = ks * 32 + q * 8 + j;
        int k = ku >> 4, u = ku & 15;
        int n = nt * 16 + c;
        int l = n >> 4, v = n & 15;
        float val = W2[(size_t)k * 768 + l * 256 + u * 16 + v] * 0.03125f;
        bfrag[t] = (_Float16)val;
    }
    if (t < 2048) {
        int nt = t >> 9, rr = t & 511;
        int lane = rr >> 3, j = rr & 7;
        int q = lane >> 4, c = lane & 15;
        int u = q * 8 + j;
        float val = (q < 2) ? W1[u * 64 + nt * 16 + c] * 0.25f : 0.0f;
        w1frag[t] = (_Float16)val;
    }
}

// int4-vectorized inclusive scan over a ZERO-PADDED region (n_pad % 32768 == 0).
__global__ __launch_bounds__(1024)
void scan_kernel(int* __restrict__ data, int n_pad) {
    __shared__ int wsum[16];
    __shared__ int carry_s;
    int tid = threadIdx.x, lane = tid & 63, wid = tid >> 6;
    if (tid == 0) carry_s = 0;
    __syncthreads();
    for (int base = 0; base < n_pad; base += 32768) {
        int beg = base + tid * 32;
        int4 c0[8];
        #pragma unroll
        for (int j = 0; j < 8; ++j)
            c0[j] = *(const int4*)(data + beg + j * 4);
        int s = 0;
        #pragma unroll
        for (int j = 0; j < 8; ++j) s += c0[j].x + c0[j].y + c0[j].z + c0[j].w;

        int v = s;
        #pragma unroll
        for (int off = 1; off < 64; off <<= 1) {
            int t = __shfl_up(v, off, 64);
            if (lane >= off) v += t;
        }
        if (lane == 63) wsum[wid] = v;
        __syncthreads();
        if (wid == 0 && lane < 16) {
            int w = wsum[lane];
            #pragma unroll
            for (int off = 1; off < 16; off <<= 1) {
                int t = __shfl_up(w, off, 16);
                if (lane >= off) w += t;
            }
            wsum[lane] = w;
        }
        __syncthreads();
        int run = carry_s + (v - s) + (wid > 0 ? wsum[wid - 1] : 0);
        #pragma unroll
        for (int j = 0; j < 8; ++j) {
            int4 o;
            run += c0[j].x; o.x = run;
            run += c0[j].y; o.y = run;
            run += c0[j].z; o.z = run;
            run += c0[j].w; o.w = run;
            *(int4*)(data + beg + j * 4) = o;
        }
        __syncthreads();
        if (tid == 1023) carry_s = run;
        __syncthreads();
    }
}

// --------------------------- MFMA edge kernel ------------------------------
// 1 wave per block; wave owns 64 edges (4 M-tiles of 16). Barrier-free.
// K-loop: register double-buffered B-frags (bA computes while bB loads).

__global__ __launch_bounds__(64, 4)
void edge_mfma_kernel(const float* __restrict__ nf, const int* __restrict__ ei,
                      const float* __restrict__ radial,
                      const _Float16* __restrict__ w1frag,
                      const float* __restrict__ sh,
                      const _Float16* __restrict__ bfrag,
                      const int* __restrict__ offs, int* __restrict__ curs,
                      unsigned int* __restrict__ rows, int E) {
    __shared__ unsigned int h_lds[64][32];   // f16 pairs (k=2t,2t+1), XOR-swizzled

    int lane = threadIdx.x & 63;
    int r_ = lane & 15;
    int q  = lane >> 4;
    int qh = q >> 1;
    int ul = (q & 1) * 8;
    unsigned int sel = qh ? 0x03020302u : 0x01000100u;

    int ebase = blockIdx.x * 64;

    // ---- phase 0: x rows for the wave's 4 M-tiles, f16 pack ----
    HW xp[4][4];
    #pragma unroll
    for (int m = 0; m < 4; ++m) {
        int e = ebase + m * 16 + r_; if (e >= E) e = E - 1;
        int src = ei[e];
        const float* xpp = nf + (size_t)src * 16 + ul;
        float4 a = *(const float4*)xpp;
        float4 b = *(const float4*)(xpp + 4);
        xp[m][0].g = __builtin_amdgcn_cvt_pkrtz(a.x, a.y);
        xp[m][1].g = __builtin_amdgcn_cvt_pkrtz(a.z, a.w);
        xp[m][2].g = __builtin_amdgcn_cvt_pkrtz(b.x, b.y);
        xp[m][3].g = __builtin_amdgcn_cvt_pkrtz(b.z, b.w);
    }

    // ---- phase 0.5: lane = edge; claim CSR slot (register p) + pack sh ----
    int p = 0;
    {
        int e = ebase + lane;
        if (e < E) {
            int dst = ei[E + e];
            p = offs[dst] + atomicAdd(&curs[dst], 1);
            const float* s = sh + (size_t)e * 9;
            float4 s03 = *(const float4*)s;
            float4 s47 = *(const float4*)(s + 4);
            float s8 = s[8];
            unsigned int* d = rows + (size_t)p * 32 + 24;
            HW w0, w1, w2, w3, w4;
            w0.g = __builtin_amdgcn_cvt_pkrtz(s03.x, s03.y);
            w1.g = __builtin_amdgcn_cvt_pkrtz(s03.z, s03.w);
            w2.g = __builtin_amdgcn_cvt_pkrtz(s47.x, s47.y);
            w3.g = __builtin_amdgcn_cvt_pkrtz(s47.z, s47.w);
            w4.g = __builtin_amdgcn_cvt_pkrtz(s8, 0.0f);
            d[0] = w0.u; d[1] = w1.u; d[2] = w2.u; d[3] = w3.u; d[4] = w4.u;
        }
    }

    // ---- phase 1: radial MLP via MFMA: z[64e][64k] = radial @ W1frag ----
    {
        BFrag wf[4];
        #pragma unroll
        for (int nt = 0; nt < 4; ++nt)
            wf[nt].u4 = *(const uint4*)(w1frag + (size_t)nt * 512 + lane * 8);

        #pragma unroll
        for (int m = 0; m < 4; ++m) {
            AFrag ra;
            if (q < 2) {
                int e = ebase + m * 16 + r_; if (e >= E) e = E - 1;
                const float* rp = radial + (size_t)e * 16 + q * 8;
                float4 a = *(const float4*)rp;
                float4 b = *(const float4*)(rp + 4);
                HW t0, t1, t2, t3;
                t0.g = __builtin_amdgcn_cvt_pkrtz(a.x, a.y);
                t1.g = __builtin_amdgcn_cvt_pkrtz(a.z, a.w);
                t2.g = __builtin_amdgcn_cvt_pkrtz(b.x, b.y);
                t3.g = __builtin_amdgcn_cvt_pkrtz(b.z, b.w);
                ra.u[0] = t0.u; ra.u[1] = t1.u; ra.u[2] = t2.u; ra.u[3] = t3.u;
            } else {
                ra.u[0] = 0; ra.u[1] = 0; ra.u[2] = 0; ra.u[3] = 0;
            }
            #pragma unroll
            for (int nt = 0; nt < 4; ++nt) {
                f32x4 z4 = __builtin_amdgcn_mfma_f32_16x16x32_f16(
                    ra.v, wf[nt].v, (f32x4){0.f, 0.f, 0.f, 0.f}, 0, 0, 0);
                #pragma unroll
                for (int i = 0; i < 4; ++i) {
                    float z = z4[i];
                    float h = z * __builtin_amdgcn_rcpf(1.0f + __expf(-z));  // silu
                    float hn = __shfl_xor(h, 1);
                    if (!(r_ & 1)) {
                        int el = m * 16 + q * 4 + i;
                        HW w; w.g = __builtin_amdgcn_cvt_pkrtz(h, hn);  // (k, k+1)
                        h_lds[el][((nt << 3) + (r_ >> 1)) ^ (el & 31)] = w.u;
                    }
                }
            }
        }
    }

    // ---- phase 2: K-loop, 32 steps of K=32; B-frags double-buffered ----
    f32x4 acc[4][3];
    #pragma unroll
    for (int m = 0; m < 4; ++m)
        #pragma unroll
        for (int nt = 0; nt < 3; ++nt)
            acc[m][nt] = (f32x4){0.f, 0.f, 0.f, 0.f};

    auto compute = [&](int ks, BFrag (&b)[3]) {
        #pragma unroll
        for (int m = 0; m < 4; ++m) {
            int el = m * 16 + r_;
            unsigned int hw = h_lds[el][ks ^ (el & 31)];
            HW hv; hv.u = __builtin_amdgcn_perm(hw, hw, sel);
            AFrag a;
            #pragma unroll
            for (int p2 = 0; p2 < 4; ++p2)
                a.h2[p2] = hv.f * xp[m][p2].f;
            #pragma unroll
            for (int nt = 0; nt < 3; ++nt)
                acc[m][nt] = __builtin_amdgcn_mfma_f32_16x16x32_f16(a.v, b[nt].v, acc[m][nt], 0, 0, 0);
        }
    };

    BFrag bA[3], bB[3];
    #pragma unroll
    for (int nt = 0; nt < 3; ++nt)
        bA[nt].u4 = *(const uint4*)(bfrag + (size_t)nt * 512 + lane * 8);
    for (int ks = 0; ks < 32; ks += 2) {
        // prefetch ks+1 while computing ks
        #pragma unroll
        for (int nt = 0; nt < 3; ++nt)
            bB[nt].u4 = *(const uint4*)(bfrag + (size_t)((ks + 1) * 3 + nt) * 512 + lane * 8);
        compute(ks, bA);
        // prefetch ks+2 (padded: ks=32 row exists as zero-pad) while computing ks+1
        #pragma unroll
        for (int nt = 0; nt < 3; ++nt)
            bA[nt].u4 = *(const uint4*)(bfrag + (size_t)((ks + 2) * 3 + nt) * 512 + lane * 8);
        compute(ks + 1, bB);
    }

    // ---- epilogue: C layout col=r_, row=q*4+i; p via shfl; 128-B rows ----
    _Float16* rowh = (_Float16*)rows;
    #pragma unroll
    for (int m = 0; m < 4; ++m) {
        #pragma unroll
        for (int i = 0; i < 4; ++i) {
            int el = m * 16 + q * 4 + i;
            int e = ebase + el;
            int pe = __shfl(p, el, 64);
            if (e < E) {
                HW pr; pr.g = __builtin_amdgcn_cvt_pkrtz(acc[m][0][i], acc[m][1][i]);
                rows[(size_t)pe * 32 + r_] = pr.u;
                rowh[(size_t)pe * 64 + 32 + r_] = (_Float16)acc[m][2][i];
            }
        }
    }
}

// ------------------------------ gather -------------------------------------
// Fused 128-B rows in CSR order -> one linear stream. Lane w<16 owns word w
// ((l0,l1) pair); lane 16+t owns word 16+t (l2 pair). Lanes 24-47 process the
// pair's second edge. sh packs live in the SAME row at words 24-28.

__global__ __launch_bounds__(256)
void gather_kernel(const unsigned int* __restrict__ rows,
                   const int* __restrict__ offs,
                   const float* __restrict__ nf, const float* __restrict__ Wsi,
                   float* __restrict__ out, int N) {
    int node = blockIdx.x * 4 + (threadIdx.x >> 6);
    if (node >= N) return;
    int lane = threadIdx.x & 63;
    int half = (lane >= 24 && lane < 48) ? 1 : 0;
    int w = lane - half * 24;              // word index for lanes < 48
    bool active = lane < 48;
    bool isP = active && (w < 16);
    bool isQ = active && (w >= 16) && (w < 24);
    int t = w - 16;

    HW accP0, accP1; accP0.u = 0; accP1.u = 0;
    HW accQ0, accQ1, accQ2, accQ3, accQ4, accQ5;
    accQ0.u = accQ1.u = accQ2.u = accQ3.u = accQ4.u = accQ5.u = 0;

    int off = offs[node], end = offs[node + 1];
    int i = off;

    auto do_pair = [&](int ibase, bool pred) {
        int idx = ibase + half;
        bool valid = !pred || (idx < end);
        int ic = valid ? idx : ibase;      // clamp to first of pair (in cache)
        const unsigned int* rb = rows + (size_t)ic * 32;
        unsigned int M = 0, Sa = 0, Sb = 0, Sc = 0;
        if (active) M = rb[w];
        if (isP) { Sa = rb[24]; Sb = rb[25]; }
        if (isQ) { Sa = rb[26]; Sb = rb[27]; Sc = rb[28]; }
        if (!valid) { Sa = 0; Sb = 0; Sc = 0; }
        HW m_, sa, sb, sc; m_.u = M; sa.u = Sa; sb.u = Sb; sc.u = Sc;
        if (isP) {
            accP0.f += m_.f * sa.f;                                    // (l0*s0, l1*s1)
            HW mh; mh.u = __builtin_amdgcn_perm(M, M, 0x03020302u);    // (l1,l1)
            accP1.f += mh.f * sb.f;                                    // (l1*s2, l1*s3)
        }
        if (isQ) {
            HW ma; ma.u = __builtin_amdgcn_perm(M, M, 0x01000100u);    // (va,va)
            HW mb; mb.u = __builtin_amdgcn_perm(M, M, 0x03020302u);    // (vb,vb)
            accQ0.f += ma.f * sa.f;   // va*(s4,s5)
            accQ1.f += ma.f * sb.f;   // va*(s6,s7)
            accQ2.f += ma.f * sc.f;   // va*(s8,0)
            accQ3.f += mb.f * sa.f;
            accQ4.f += mb.f * sb.f;
            accQ5.f += mb.f * sc.f;
        }
    };

    // main: 4 pairs (8 edges) per round, no predication (loads hoist freely)
    for (; i + 7 < end; i += 8) {
        #pragma unroll
        for (int jp = 0; jp < 4; ++jp) do_pair(i + 2 * jp, false);
    }
    // tail: predicated pairs
    for (; i < end; i += 2) do_pair(i, true);

    // fold half=1 into half=0 lanes (lanes >=48 hold zeros)
    {
        int o;
        o = __shfl((int)accP0.u, lane + 24, 64); if (lane < 24) { HW h_; h_.u = (unsigned)o; accP0.f += h_.f; }
        o = __shfl((int)accP1.u, lane + 24, 64); if (lane < 24) { HW h_; h_.u = (unsigned)o; accP1.f += h_.f; }
        o = __shfl((int)accQ0.u, lane + 24, 64); if (lane < 24) { HW h_; h_.u = (unsigned)o; accQ0.f += h_.f; }
        o = __shfl((int)accQ1.u, lane + 24, 64); if (lane < 24) { HW h_; h_.u = (unsigned)o; accQ1.f += h_.f; }
        o = __shfl((int)accQ2.u, lane + 24, 64); if (lane < 24) { HW h_; h_.u = (unsigned)o; accQ2.f += h_.f; }
        o = __shfl((int)accQ3.u, lane + 24, 64); if (lane < 24) { HW h_; h_.u = (unsigned)o; accQ3.f += h_.f; }
        o = __shfl((int)accQ4.u, lane + 24, 64); if (lane < 24) { HW h_; h_.u = (unsigned)o; accQ4.f += h_.f; }
        o = __shfl((int)accQ5.u, lane + 24, 64); if (lane < 24) { HW h_; h_.u = (unsigned)o; accQ5.f += h_.f; }
    }

    if (lane >= 24) return;
    float* orow = out + (size_t)node * 144;
    if (w < 16) {
        float c0 = (float)accP0.f[0];          // ch w (l0)
        float c1 = (float)accP0.f[1];          // ch 16+3w
        float c2 = (float)accP1.f[0];          // ch 16+3w+1
        float c3 = (float)accP1.f[1];          // ch 16+3w+2
        const float* xr = nf + (size_t)node * 16;
        float si = 0.0f;
        #pragma unroll
        for (int u = 0; u < 16; ++u)
            si = fmaf(xr[u], Wsi[u * 16 + w], si);
        c0 = fmaf(si, 0.25f, c0);
        orow[w] = c0;
        orow[16 + 3 * w + 0] = c1;
        orow[16 + 3 * w + 1] = c2;
        orow[16 + 3 * w + 2] = c3;
    } else {
        float* qp = orow + 64 + 10 * t;
        qp[0] = (float)accQ0.f[0]; qp[1] = (float)accQ0.f[1];
        qp[2] = (float)accQ1.f[0]; qp[3] = (float)accQ1.f[1];
        qp[4] = (float)accQ2.f[0];
        qp[5] = (float)accQ3.f[0]; qp[6] = (float)accQ3.f[1];
        qp[7] = (float)accQ4.f[0]; qp[8] = (float)accQ4.f[1];
        qp[9] = (float)accQ5.f[0];
    }
}

// ------------------------- fallback (atomic path) --------------------------

__global__ __launch_bounds__(256)
void si_init_kernel(const float* __restrict__ nf, const float* __restrict__ Wsi,
                    float* __restrict__ out, int N) {
    int t = blockIdx.x * blockDim.x + threadIdx.x;
    int total = N * 144;
    if (t >= total) return;
    int n = t / 144;
    int c = t - n * 144;
    float val = 0.0f;
    if (c < 16) {
        const float* xr = nf + n * 16;
        #pragma unroll
        for (int u = 0; u < 16; ++u)
            val = fmaf(xr[u], Wsi[u * 16 + c], val);
        val *= 0.25f;
    }
    out[t] = val;
}

__global__ __launch_bounds__(256)
void edge_kernel_atomic(const float* __restrict__ nf, const int* __restrict__ ei,
                        const float* __restrict__ sh, const float* __restrict__ radial,
                        const float* __restrict__ W1, const float* __restrict__ W2,
                        float* __restrict__ out, int E) {
    int e = blockIdx.x * blockDim.x + threadIdx.x;
    if (e >= E) return;
    int src = ei[e];
    int dst = ei[E + e];
    float r[16], x[16];
    #pragma unroll
    for (int u = 0; u < 16; ++u) r[u] = radial[e * 16 + u] * 0.25f;
    #pragma unroll
    for (int u = 0; u < 16; ++u) x[u] = nf[src * 16 + u] * 0.03125f;
    float acc[48];
    #pragma unroll
    for (int j = 0; j < 48; ++j) acc[j] = 0.0f;
    for (int k = 0; k < 64; ++k) {
        float z = 0.0f;
        #pragma unroll
        for (int u = 0; u < 16; ++u) z = fmaf(r[u], W1[u * 64 + k], z);
        float hk = z / (1.0f + __expf(-z));
        const float* w2k = W2 + k * 768;
        #pragma unroll 4
        for (int u = 0; u < 16; ++u) {
            float p = hk * x[u];
            const float* w = w2k + u * 16;
            #pragma unroll
            for (int l = 0; l < 3; ++l)
                #pragma unroll
                for (int v = 0; v < 16; ++v)
                    acc[l * 16 + v] = fmaf(p, w[l * 256 + v], acc[l * 16 + v]);
        }
    }
    const float* she = sh + e * 9;
    float* orow = out + (long)dst * 144;
    #pragma unroll
    for (int v = 0; v < 16; ++v) atomicAdd(&orow[v], acc[v] * she[0]);
    #pragma unroll
    for (int v = 0; v < 16; ++v)
        for (int m = 0; m < 3; ++m)
            atomicAdd(&orow[16 + v * 3 + m], acc[16 + v] * she[1 + m]);
    #pragma unroll
    for (int v = 0; v < 16; ++v)
        for (int m = 0; m < 5; ++m)
            atomicAdd(&orow[64 + v * 5 + m], acc[32 + v] * she[4 + m]);
}

// ---------------------------------------------------------------------------

extern "C" void kernel_launch(void* const* d_in, const int* in_sizes, int n_in,
                              void* d_out, int out_size, void* d_ws, size_t ws_size,
                              hipStream_t stream) {
    const float* nf     = (const float*)d_in[0];
    const int*   ei     = (const int*)  d_in[1];
    const float* sh     = (const float*)d_in[2];
    const float* radial = (const float*)d_in[3];
    const float* W1     = (const float*)d_in[4];
    const float* W2     = (const float*)d_in[5];
    const float* Wsi    = (const float*)d_in[6];
    float* out = (float*)d_out;

    const int N = in_sizes[0] / 16;
    const int E = in_sizes[1] / 2;

    int n_scan = N + 1;
    int n_pad  = (n_scan + 32767) & ~32767;

    size_t rows_bytes = (size_t)E * 128;                     // fused 128-B rows
    size_t offs_bytes = (size_t)n_pad * sizeof(int);
    size_t curs_bytes = (size_t)N * sizeof(int);
    size_t bfrag_off  = (rows_bytes + offs_bytes + curs_bytes + 127) & ~(size_t)127;
    size_t bfrag_bytes = 102 * 512 * sizeof(_Float16);       // 96KB + 6KB pad (ks=32,33 prefetch)
    size_t w1f_off    = bfrag_off + bfrag_bytes;
    size_t w1f_bytes  = 2048 * sizeof(_Float16);             // 4 KB
    size_t need = w1f_off + w1f_bytes;

    if (ws_size < need) {
        int total = N * 144;
        hipLaunchKernelGGL(si_init_kernel, dim3((total + 255) / 256), dim3(256), 0, stream,
                           nf, Wsi, out, N);
        hipLaunchKernelGGL(edge_kernel_atomic, dim3((E + 255) / 256), dim3(256), 0, stream,
                           nf, ei, sh, radial, W1, W2, out, E);
        return;
    }

    char* wsb = (char*)d_ws;
    unsigned int* rows = (unsigned int*)wsb;
    int*   offs = (int*)(wsb + rows_bytes);
    int*   curs = (int*)(wsb + rows_bytes + offs_bytes);
    _Float16* bfrag = (_Float16*)(wsb + bfrag_off);
    _Float16* w1frag = (_Float16*)(wsb + w1f_off);

    (void)hipMemsetAsync(offs, 0, offs_bytes + curs_bytes, stream);

    int eb256 = (E + 255) / 256;
    hipLaunchKernelGGL(prep_kernel, dim3(eb256), dim3(256), 0, stream,
                       W2, W1, bfrag, w1frag, ei, offs, E);
    hipLaunchKernelGGL(scan_kernel, dim3(1), dim3(1024), 0, stream, offs, n_pad);
    int eb64 = (E + 63) / 64;
    hipLaunchKernelGGL(edge_mfma_kernel, dim3(eb64), dim3(64), 0, stream,
                       nf, ei, radial, w1frag, sh, bfrag, offs, curs, rows, E);
    hipLaunchKernelGGL(gather_kernel, dim3((N + 3) / 4), dim3(256), 0, stream,
                       rows, offs, nf, Wsi, out, N);
}